// Round 7
// baseline (316.610 us; speedup 1.0000x reference)
//
#include <hip/hip_runtime.h>
#include <hip/hip_bf16.h>

#define B_N 16
#define LP_N 1024
#define LQ_N 1024
#define H_N 1024

typedef unsigned short u16;
typedef __attribute__((ext_vector_type(8))) short bf16x8;
typedef __attribute__((ext_vector_type(4))) float f32x4;

__device__ __forceinline__ u16 f2bf(float x) {
    __hip_bfloat16 h = __float2bfloat16(x);
    return *(u16*)&h;
}
__device__ __forceinline__ float bf2f(u16 u) {
    __hip_bfloat16 h;
    *(u16*)&h = u;
    return __bfloat162float(h);
}

__device__ __forceinline__ void load_lds16(const u16* g, u16* l) {
    __builtin_amdgcn_global_load_lds(
        (const __attribute__((address_space(1))) void*)g,
        (__attribute__((address_space(3))) void*)l, 16, 0, 0);
}

#define MFMA_B16(a, b, c) __builtin_amdgcn_mfma_f32_16x16x32_bf16(a, b, c, 0, 0, 0)
#define VMW(N)  asm volatile("s_waitcnt vmcnt(" #N ")" ::: "memory")
#define LGKM8() asm volatile("s_waitcnt lgkmcnt(8)" ::: "memory")
#define LGKM0() asm volatile("s_waitcnt lgkmcnt(0)" ::: "memory")
#define SCHB()  __builtin_amdgcn_sched_barrier(0)
#define SBAR()  __builtin_amdgcn_s_barrier()

// ---------------------------------------------------------------------------
// 256x256 dense-bf16 MFMA GEMM, NT form, m201-faithful 4-phase K-tile schedule.
// K virtualized over SEGS segments of 1024 (split-bf16 = K-concat of
// [Ahi|Ahi|Alo] x [Bhi|Blo|Bhi]). BK=64, 8 waves (2M x 4N).
// INTERLEAVED wave rows: wave wr owns rows wr*64+[0,64) U wr*64+128+[0,64),
// so ALL waves read A-half0 (rows[0,128)) in phases 0-1 and A-half1 in 2-3.
// Phase p (p=0..3): { ds_read 4 A-frags (+8 B-frags at p0, held in regs all
// tile) -> issue 1 half-tile stage of t+1 (order B0,B1,A0,A1) ->
// [vmcnt(4)@p1 / vmcnt(2)@p3, counted, never 0] -> s_barrier -> lgkmcnt(0)
// + sched_barrier (rule #18) -> setprio(1) 16 MFMA setprio(0) -> s_barrier }.
// FIFO: vmcnt(4)@p1 retires THIS tile's A1 (issued 2 phases ago, needed
// p2); vmcnt(2)@p3 retires next tile's B0,B1,A0 (issued 1-3 phases ago,
// needed next p0). ds_reads sit BEFORE the barrier so latency hides in the
// barrier wait. Prologue + last tile use a one-time vmcnt(0).
// Swizzle (R6-verified, 0 conflicts): 16B slot s_phys = s_log ^ (row&7);
// linear LDS dest (m104), pre-swizzled global source, swizzled ds_read.
// EPI: 0 = fp32 store, 1 = +bias & split bf16 hi/lo store, 2 = relu fp32.
// ---------------------------------------------------------------------------
template<int SEGS, int EPI>
__launch_bounds__(512, 2)
__global__ void gemm_pipe(const u16* __restrict__ pa0, const u16* __restrict__ pa1,
                          const u16* __restrict__ pa2,
                          const u16* __restrict__ pb0, const u16* __restrict__ pb1,
                          const u16* __restrict__ pb2,
                          const float* __restrict__ bias,
                          float* __restrict__ Cf, u16* __restrict__ Chi, u16* __restrict__ Clo,
                          int N, int gn, int gmn,
                          long long sA, long long sB, long long sC)
{
    __shared__ __align__(16) u16 lds[65536];     // 2 x (A 32KB + B 32KB)

    const int tid  = threadIdx.x;
    const int lane = tid & 63;
    const int wv   = tid >> 6;
    const int wr   = wv >> 2, wc = wv & 3;       // 2M x 4N waves

    // XCD-contiguous block swizzle (nwg=256 -> 32 contiguous tiles/XCD)
    const int d   = blockIdx.x;
    const int cpx = gridDim.x >> 3;
    const int swz = (d & 7) * cpx + (d >> 3);
    const long long z = swz / gmn;
    const int r_  = swz % gmn;
    const int bm  = (r_ / gn) * 256;
    const int bn  = (r_ % gn) * 256;

    const char* A0 = (const char*)(pa0 + z * sA);
    const char* A1 = (const char*)(pa1 + z * sA);
    const char* A2 = (const char*)(pa2 + z * sA);
    const char* B0 = (const char*)(pb0 + z * sB);
    const char* B1 = (const char*)(pb1 + z * sB);
    const char* B2 = (const char*)(pb2 + z * sB);

    // ---- staging geometry (R6-verified): half-tile = 128 rows x 64 cols.
    // chunk c (1024/half): row=c>>3, phys slot=c&7, src slot=(c&7)^(row&7).
    // thread stages chunks {tid, tid+512} (rows r0, r0+64; same XOR).
    const int r0 = tid >> 3;                     // 0..63
    const int xc = (tid & 7) ^ (r0 & 7);
    const long long aoff = (long long)(bm + r0) * 2048 + xc * 16;
    const long long boff = (long long)(bn + r0) * 2048 + xc * 16;
    const int dA = tid * 8;                      // u16 dest offset, A region
    const int dB = 16384 + tid * 8;              // B region

    // ---- fragment ds_read offsets (u16 units), same swizzle
    const int sl0 = (((lane >> 4) + 0) ^ (lane & 7)) * 8;   // subk 0 slot
    const int sl1 = (((lane >> 4) + 4) ^ (lane & 7)) * 8;   // subk 1 slot
    const int rbA2 = (wr * 64 + (lane & 15)) * 64;          // interleaved rows
    const int rbB  = 16384 + (wc * 64 + (lane & 15)) * 64;

    f32x4 acc[8][4];
#pragma unroll
    for (int i = 0; i < 8; ++i)
#pragma unroll
        for (int j = 0; j < 4; ++j)
            acc[i][j] = (f32x4){0.f, 0.f, 0.f, 0.f};

    bf16x8 bb0[4], bb1[4];      // B frags (subk0/1), live whole tile
    bf16x8 a00, a01, a10, a11;  // A frags of the current phase

#define STG_B(H, NB) do {                                                     \
        load_lds16((const u16*)(bseg + boff + kb + (H) * 262144),             \
                   lds + (NB) + (H) * 8192 + dB);                             \
        load_lds16((const u16*)(bseg + boff + kb + (H) * 262144 + 131072),    \
                   lds + (NB) + (H) * 8192 + dB + 4096);                      \
    } while (0)
#define STG_A(H, NB) do {                                                     \
        load_lds16((const u16*)(aseg + aoff + kb + (H) * 262144),             \
                   lds + (NB) + (H) * 8192 + dA);                             \
        load_lds16((const u16*)(aseg + aoff + kb + (H) * 262144 + 131072),    \
                   lds + (NB) + (H) * 8192 + dA + 4096);                      \
    } while (0)
// phase P A-frags: rows = wr*64 + (P>>1)*128 + (P&1)*32 + f*16 + (lane&15)
#define RD_AP(P, CB) do {                                                     \
        const int pb_ = (CB) + rbA2 + (((P) >> 1) * 128 + ((P) & 1) * 32) * 64; \
        a00 = *(const bf16x8*)(lds + pb_ + sl0);                              \
        a01 = *(const bf16x8*)(lds + pb_ + sl1);                              \
        a10 = *(const bf16x8*)(lds + pb_ + 1024 + sl0);                       \
        a11 = *(const bf16x8*)(lds + pb_ + 1024 + sl1);                       \
    } while (0)
#define RD_B(CB) do {                                                         \
        _Pragma("unroll")                                                     \
        for (int j = 0; j < 4; ++j) {                                         \
            bb0[j] = *(const bf16x8*)(lds + (CB) + rbB + j * 1024 + sl0);     \
            bb1[j] = *(const bf16x8*)(lds + (CB) + rbB + j * 1024 + sl1);     \
        }                                                                     \
    } while (0)
#define PH_MFMA(P) do {                                                       \
        __builtin_amdgcn_s_setprio(1);                                        \
        _Pragma("unroll")                                                     \
        for (int j = 0; j < 4; ++j) {                                         \
            acc[2 * (P)][j]     = MFMA_B16(a00, bb0[j], acc[2 * (P)][j]);     \
            acc[2 * (P)][j]     = MFMA_B16(a01, bb1[j], acc[2 * (P)][j]);     \
            acc[2 * (P) + 1][j] = MFMA_B16(a10, bb0[j], acc[2 * (P) + 1][j]); \
            acc[2 * (P) + 1][j] = MFMA_B16(a11, bb1[j], acc[2 * (P) + 1][j]); \
        }                                                                     \
        __builtin_amdgcn_s_setprio(0);                                        \
    } while (0)

    const int NT = SEGS * 16;                    // K-tiles of 64

    // prologue: stage tile 0 fully, one-time drain + publish
    {
        const char* aseg = A0;
        const char* bseg = B0;
        const long long kb = 0;
        STG_B(0, 0); STG_B(1, 0); STG_A(0, 0); STG_A(1, 0);
        VMW(0);
        SBAR();
    }

    for (int t = 0; t < NT; ++t) {
        const int cb = (t & 1) << 15;
        const int nb = ((t + 1) & 1) << 15;
        const bool st = (t + 1) < NT;
        const int s_ = (t + 1) >> 4;
        const long long kb = (long long)(((t + 1) & 15) * 128);
        const char* aseg = (SEGS == 1) ? A0 : (s_ == 0 ? A0 : (s_ == 1 ? A1 : A2));
        const char* bseg = (SEGS == 1) ? B0 : (s_ == 0 ? B0 : (s_ == 1 ? B1 : B2));

        // phase 0: rows wr*64+[0,32)  (A-half0) + all B frags
        RD_B(cb);
        RD_AP(0, cb);
        if (st) STG_B(0, nb);
        LGKM8();
        SBAR();
        LGKM0(); SCHB();
        PH_MFMA(0);
        SBAR();
        // phase 1: rows wr*64+[32,64)  (A-half0)
        RD_AP(1, cb);
        if (st) STG_B(1, nb);
        if (st) { VMW(4); } else { VMW(0); }   // retire THIS tile's A1 (needed p2)
        SBAR();
        LGKM0(); SCHB();
        PH_MFMA(1);
        SBAR();
        // phase 2: rows wr*64+128+[0,32)  (A-half1)
        RD_AP(2, cb);
        if (st) STG_A(0, nb);
        SBAR();
        LGKM0(); SCHB();
        PH_MFMA(2);
        SBAR();
        // phase 3: rows wr*64+128+[32,64)  (A-half1)
        RD_AP(3, cb);
        if (st) STG_A(1, nb);
        if (st) { VMW(2); }                    // retire next tile's B0,B1,A0
        SBAR();
        LGKM0(); SCHB();
        PH_MFMA(3);
        SBAR();
    }
#undef STG_B
#undef STG_A
#undef RD_AP
#undef RD_B
#undef PH_MFMA

    // epilogue; C/D map: col = lane&15, row = (lane>>4)*4 + e  [m89/m91]
    // acc[i]: i = 2*P+f -> row block = wr*64 + (i>>2)*128 + ((i>>1)&1)*32 + (i&1)*16
    const long long Cbase = z * sC;
#pragma unroll
    for (int i = 0; i < 8; ++i) {
        const int prow = (i >> 2) * 128 + ((i >> 1) & 1) * 32 + (i & 1) * 16;
        const int row0 = bm + wr * 64 + prow + ((lane >> 4) << 2);
#pragma unroll
        for (int j = 0; j < 4; ++j) {
            const int col = bn + wc * 64 + j * 16 + (lane & 15);
#pragma unroll
            for (int e = 0; e < 4; ++e) {
                const float v = acc[i][j][e];
                const long long idx = Cbase + (long long)(row0 + e) * N + col;
                if constexpr (EPI == 0) {
                    Cf[idx] = v;
                } else if constexpr (EPI == 1) {
                    const float vb = v + bias[col];
                    const u16 h = f2bf(vb);
                    Chi[idx] = h;
                    Clo[idx] = f2bf(vb - bf2f(h));
                } else {
                    Cf[idx] = fmaxf(v, 0.f);
                }
            }
        }
    }
}

// fp32 -> bf16 hi/lo split, 4 elems/thread
__global__ void split_cvt(const float* __restrict__ in, u16* __restrict__ hi,
                          u16* __restrict__ lo, long long n4)
{
    const long long i = (long long)blockIdx.x * 256 + threadIdx.x;
    if (i >= n4) return;
    const float4 v = ((const float4*)in)[i];
    ushort4 h, l;
    h.x = f2bf(v.x); l.x = f2bf(v.x - bf2f(h.x));
    h.y = f2bf(v.y); l.y = f2bf(v.y - bf2f(h.y));
    h.z = f2bf(v.z); l.z = f2bf(v.z - bf2f(h.z));
    h.w = f2bf(v.w); l.w = f2bf(v.w - bf2f(h.w));
    ((ushort4*)hi)[i] = h;
    ((ushort4*)lo)[i] = l;
}

// out[c][r] = in[r][c] with bf16 (hi[,lo]) conversion; in: R x C per batch z
template<bool LO>
__global__ void transpose_cvt(const float* __restrict__ in, u16* __restrict__ hi,
                              u16* __restrict__ lo, int R, int C,
                              long long sIn, long long sOut)
{
    __shared__ float t[32][33];
    const long long z = blockIdx.z;
    const float* I = in + z * sIn;
    const int r0 = blockIdx.y * 32, c0 = blockIdx.x * 32;
    for (int j = threadIdx.y; j < 32; j += 8)
        t[j][threadIdx.x] = I[(long long)(r0 + j) * C + c0 + threadIdx.x];
    __syncthreads();
    for (int j = threadIdx.y; j < 32; j += 8) {
        const float v = t[threadIdx.x][j];
        const long long o = z * sOut + (long long)(c0 + j) * R + r0 + threadIdx.x;
        const u16 h = f2bf(v);
        hi[o] = h;
        if (LO) lo[o] = f2bf(v - bf2f(h));
    }
}

// row softmax (fp32 in, bf16 out), one 256-thread block per 1024-elem row
__global__ void softmax_bf16(const float* __restrict__ S, u16* __restrict__ A)
{
    const long long row = blockIdx.x;
    const float* r = S + row * (long long)LQ_N;
    const int t = threadIdx.x;
    float4 v = ((const float4*)r)[t];

    float m = fmaxf(fmaxf(v.x, v.y), fmaxf(v.z, v.w));
#pragma unroll
    for (int off = 32; off > 0; off >>= 1)
        m = fmaxf(m, __shfl_xor(m, off));

    __shared__ float red[4];
    const int lane = t & 63, wid = t >> 6;
    if (lane == 0) red[wid] = m;
    __syncthreads();
    m = fmaxf(fmaxf(red[0], red[1]), fmaxf(red[2], red[3]));
    __syncthreads();

    v.x = __expf(v.x - m); v.y = __expf(v.y - m);
    v.z = __expf(v.z - m); v.w = __expf(v.w - m);
    float s = v.x + v.y + v.z + v.w;
#pragma unroll
    for (int off = 32; off > 0; off >>= 1)
        s += __shfl_xor(s, off);
    if (lane == 0) red[wid] = s;
    __syncthreads();
    s = red[0] + red[1] + red[2] + red[3];

    const float inv = 1.0f / s;
    ushort4 o;
    o.x = f2bf(v.x * inv); o.y = f2bf(v.y * inv);
    o.z = f2bf(v.z * inv); o.w = f2bf(v.w * inv);
    ((ushort4*)(A + row * (long long)LQ_N))[t] = o;
}

// ---------------------------------------------------------------------------
// Fallback fp32 path (round-1, verified; needs only 128 MB ws)
// ---------------------------------------------------------------------------
#define BM 128
#define BN 128
#define BK 8
#define TM 8
#define TN 8

template<bool TRANSB, bool BIAS, bool RELU>
__launch_bounds__(256)
__global__ void gemm_k(const float* __restrict__ A, const float* __restrict__ Bmat,
                       const float* __restrict__ bias, float* __restrict__ C,
                       int M, int N, int K,
                       long long sA, long long sB, long long sC)
{
    __shared__ float As[BK][BM];
    __shared__ float Bs[BK][BN];
    const int tid = threadIdx.x;
    const int tx = tid & 15;
    const int ty = tid >> 4;
    const int bn = blockIdx.x * BN;
    const int bm = blockIdx.y * BM;
    const long long z = blockIdx.z;
    A += z * sA; Bmat += z * sB; C += z * sC;
    float acc[TM][TN];
#pragma unroll
    for (int i = 0; i < TM; i++)
#pragma unroll
        for (int j = 0; j < TN; j++) acc[i][j] = 0.f;
    const int arow = tid >> 1;
    const int acol = (tid & 1) * 4;
    const int bk_n = tid >> 5;
    const int bn_n = (tid & 31) * 4;
    for (int k0 = 0; k0 < K; k0 += BK) {
        float4 a4 = *(const float4*)&A[(long long)(bm + arow) * K + k0 + acol];
        As[acol + 0][arow] = a4.x; As[acol + 1][arow] = a4.y;
        As[acol + 2][arow] = a4.z; As[acol + 3][arow] = a4.w;
        if (TRANSB) {
            float4 b4 = *(const float4*)&Bmat[(long long)(bn + arow) * K + k0 + acol];
            Bs[acol + 0][arow] = b4.x; Bs[acol + 1][arow] = b4.y;
            Bs[acol + 2][arow] = b4.z; Bs[acol + 3][arow] = b4.w;
        } else {
            float4 b4 = *(const float4*)&Bmat[(long long)(k0 + bk_n) * N + bn + bn_n];
            *(float4*)&Bs[bk_n][bn_n] = b4;
        }
        __syncthreads();
#pragma unroll
        for (int k = 0; k < BK; k++) {
            float a[TM], b[TN];
            *(float4*)&a[0] = *(const float4*)&As[k][ty * TM];
            *(float4*)&a[4] = *(const float4*)&As[k][ty * TM + 4];
            *(float4*)&b[0] = *(const float4*)&Bs[k][tx * TN];
            *(float4*)&b[4] = *(const float4*)&Bs[k][tx * TN + 4];
#pragma unroll
            for (int i = 0; i < TM; i++)
#pragma unroll
                for (int j = 0; j < TN; j++)
                    acc[i][j] = fmaf(a[i], b[j], acc[i][j]);
        }
        __syncthreads();
    }
#pragma unroll
    for (int i = 0; i < TM; i++) {
        const int row = bm + ty * TM + i;
#pragma unroll
        for (int j = 0; j < TN; j += 4) {
            const int col = bn + tx * TN + j;
            float4 v;
            v.x = acc[i][j + 0]; v.y = acc[i][j + 1];
            v.z = acc[i][j + 2]; v.w = acc[i][j + 3];
            if (BIAS) {
                v.x += bias[col + 0]; v.y += bias[col + 1];
                v.z += bias[col + 2]; v.w += bias[col + 3];
            }
            if (RELU) {
                v.x = fmaxf(v.x, 0.f); v.y = fmaxf(v.y, 0.f);
                v.z = fmaxf(v.z, 0.f); v.w = fmaxf(v.w, 0.f);
            }
            *(float4*)&C[(long long)row * N + col] = v;
        }
    }
}

__global__ void softmax_k(float* __restrict__ S)
{
    const long long row = blockIdx.x;
    float* r = S + row * (long long)LQ_N;
    const int t = threadIdx.x;
    float4 v = ((float4*)r)[t];
    float m = fmaxf(fmaxf(v.x, v.y), fmaxf(v.z, v.w));
#pragma unroll
    for (int off = 32; off > 0; off >>= 1)
        m = fmaxf(m, __shfl_xor(m, off));
    __shared__ float red[4];
    const int lane = t & 63, wid = t >> 6;
    if (lane == 0) red[wid] = m;
    __syncthreads();
    m = fmaxf(fmaxf(red[0], red[1]), fmaxf(red[2], red[3]));
    __syncthreads();
    v.x = __expf(v.x - m); v.y = __expf(v.y - m);
    v.z = __expf(v.z - m); v.w = __expf(v.w - m);
    float s = v.x + v.y + v.z + v.w;
#pragma unroll
    for (int off = 32; off > 0; off >>= 1)
        s += __shfl_xor(s, off);
    if (lane == 0) red[wid] = s;
    __syncthreads();
    s = red[0] + red[1] + red[2] + red[3];
    const float inv = 1.0f / s;
    v.x *= inv; v.y *= inv; v.z *= inv; v.w *= inv;
    ((float4*)r)[t] = v;
}

extern "C" void kernel_launch(void* const* d_in, const int* in_sizes, int n_in,
                              void* d_out, int out_size, void* d_ws, size_t ws_size,
                              hipStream_t stream)
{
    const float* p    = (const float*)d_in[0];
    const float* q    = (const float*)d_in[1];
    const float* W    = (const float*)d_in[2];
    const float* bias = (const float*)d_in[3];
    float* out = (float*)d_out;

    const size_t MB32 = 33554432ull;                 // 16M bf16
    const size_t NEED = 7 * MB32 + 2 * 2097152ull;   // 228 MB + 4 MB

    if (ws_size >= NEED) {
        char* w = (char*)d_ws;
        u16* p_hi    = (u16*)(w + 0 * MB32);
        u16* p_lo    = (u16*)(w + 1 * MB32);
        u16* q_hi    = (u16*)(w + 2 * MB32);
        u16* q_lo    = (u16*)(w + 3 * MB32);
        u16* keys_hi = (u16*)(w + 4 * MB32);
        u16* keys_lo = (u16*)(w + 5 * MB32);
        u16* qT_hi   = (u16*)(w + 6 * MB32);
        u16* Wt_hi   = (u16*)(w + 7 * MB32);
        u16* Wt_lo   = (u16*)(w + 7 * MB32 + 2097152);
        float* scores = (float*)(w + 2 * MB32);  // reuses q_hi/q_lo after GEMM1
        u16* attn     = (u16*)(w + 0 * MB32);    // reuses p_hi after GEMM2

        const long long n4 = (long long)B_N * LQ_N * H_N / 4;
        split_cvt<<<dim3((unsigned)(n4 / 256)), 256, 0, stream>>>(p, p_hi, p_lo, n4);
        split_cvt<<<dim3((unsigned)(n4 / 256)), 256, 0, stream>>>(q, q_hi, q_lo, n4);
        transpose_cvt<true><<<dim3(32, 32, 1), dim3(32, 8), 0, stream>>>(
            W, Wt_hi, Wt_lo, H_N, H_N, 0, 0);
        transpose_cvt<false><<<dim3(32, 32, B_N), dim3(32, 8), 0, stream>>>(
            q, qT_hi, nullptr, LQ_N, H_N,
            (long long)LQ_N * H_N, (long long)LQ_N * H_N);

        // keys = q @ W + b : K-concat [q_hi|q_hi|q_lo] x [W_hi|W_lo|W_hi].
        // M=16384 (batch folded), N=1024. grid 64x4 = 256.
        gemm_pipe<3, 1><<<256, 512, 0, stream>>>(
            q_hi, q_hi, q_lo, Wt_hi, Wt_lo, Wt_hi, bias,
            nullptr, keys_hi, keys_lo,
            H_N, /*gn=*/4, /*gmn=*/256, 0, 0, 0);

        // scores[b] = p[b] @ keys[b]^T : [p_hi|p_hi|p_lo] x [k_hi|k_lo|k_hi].
        gemm_pipe<3, 0><<<256, 512, 0, stream>>>(
            p_hi, p_hi, p_lo, keys_hi, keys_lo, keys_hi, nullptr,
            scores, nullptr, nullptr,
            LQ_N, /*gn=*/4, /*gmn=*/16,
            (long long)LP_N * H_N, (long long)LQ_N * H_N, (long long)LP_N * LQ_N);

        softmax_bf16<<<B_N * LP_N, 256, 0, stream>>>(scores, attn);

        // out[b] = relu(attn[b] @ q[b]) : dense bf16, K=1024.
        gemm_pipe<1, 2><<<256, 512, 0, stream>>>(
            attn, attn, attn, qT_hi, qT_hi, qT_hi, nullptr,
            out, nullptr, nullptr,
            H_N, /*gn=*/4, /*gmn=*/16,
            (long long)LP_N * LQ_N, (long long)H_N * LQ_N, (long long)LP_N * H_N);
    } else {
        float* keys   = (float*)d_ws;
        float* scores = keys + (long long)B_N * LQ_N * H_N;

        gemm_k<false, true, false><<<dim3(H_N / BN, (B_N * LQ_N) / BM, 1), 256, 0, stream>>>(
            q, W, bias, keys, B_N * LQ_N, H_N, H_N, 0, 0, 0);
        gemm_k<true, false, false><<<dim3(LQ_N / BN, LP_N / BM, B_N), 256, 0, stream>>>(
            p, keys, nullptr, scores, LP_N, LQ_N, H_N,
            (long long)LP_N * H_N, (long long)LQ_N * H_N, (long long)LP_N * LQ_N);
        softmax_k<<<B_N * LP_N, 256, 0, stream>>>(scores);
        gemm_k<false, false, true><<<dim3(H_N / BN, LP_N / BM, B_N), 256, 0, stream>>>(
            scores, q, nullptr, out, LP_N, H_N, LQ_N,
            (long long)LP_N * LQ_N, (long long)LQ_N * H_N, (long long)LP_N * H_N);
    }
}

// Round 8
// 309.851 us; speedup vs baseline: 1.0218x; 1.0218x over previous
//
#include <hip/hip_runtime.h>
#include <hip/hip_bf16.h>

#define B_N 16
#define LP_N 1024
#define LQ_N 1024
#define H_N 1024

typedef unsigned short u16;
typedef __attribute__((ext_vector_type(8))) short bf16x8;
typedef __attribute__((ext_vector_type(4))) float f32x4;

__device__ __forceinline__ u16 f2bf(float x) {
    __hip_bfloat16 h = __float2bfloat16(x);
    return *(u16*)&h;
}
__device__ __forceinline__ float bf2f(u16 u) {
    __hip_bfloat16 h;
    *(u16*)&h = u;
    return __bfloat162float(h);
}

__device__ __forceinline__ void load_lds16(const u16* g, u16* l) {
    __builtin_amdgcn_global_load_lds(
        (const __attribute__((address_space(1))) void*)g,
        (__attribute__((address_space(3))) void*)l, 16, 0, 0);
}

#define MFMA_B16(a, b, c) __builtin_amdgcn_mfma_f32_16x16x32_bf16(a, b, c, 0, 0, 0)
#define VMW0()  asm volatile("s_waitcnt vmcnt(0)" ::: "memory")
#define LGKM0() asm volatile("s_waitcnt lgkmcnt(0)" ::: "memory")
#define SCHB()  __builtin_amdgcn_sched_barrier(0)
#define SBAR()  __builtin_amdgcn_s_barrier()

// ---------------------------------------------------------------------------
// 256x256 split-bf16 MFMA GEMM, NT form, SHARED-OPERAND staging (R8).
// R6 post-mortem: per-tile time == MFMA cyc + LDS cyc (serial sum). So cut
// LDS bytes: instead of K-concat [Ahi|Ahi|Alo]x[Bhi|Blo|Bhi] (stages/reads
// Ahi and Bhi TWICE), use BK=32 tiles staging {Ahi, Alo, Bhi, Blo} each ONCE
// (4 x 16KB regions, dbuf = 128KB) and compute all 3 split terms per tile:
//   T1 = ah x bh;  T2 = ah x bl (reuses ah regs, zero extra reads);
//   T3 = al x bh.
// LDS reads/GEMM: 6144 b128 vs 9216 (-33%); writes -33%; HBM fetch -23%.
// Schedule = R6's proven loop: per tile ONE vmcnt(0) gate + ONE s_barrier;
// all 8 staging loads for t+1 issued right after the front reads (max gate
// slack ~1 tile); al reads issued after T1 so their latency hides under T2.
// 96 MFMA/wave/tile vs 24 ds_read_b128 (4:1).
// Swizzle: row of 32 bf16 = 4 x 16B slots; phys slot = log ^ (row&3);
// linear LDS dest (m104), pre-swizzled global source, swizzled ds_read
// (both-sides, rule #21). Frag read covers all 64 slots of 16 rows ->
// exactly 8 touches/bank (b128 floor, balanced).
// DENSE=true: 2 regions {A, B}, T1 only (GEMM3). All row strides 2048B.
// EPI: 0 = fp32 store, 1 = +bias & split bf16 hi/lo store, 2 = relu fp32.
// ---------------------------------------------------------------------------
template<bool DENSE, int EPI>
__launch_bounds__(512, 2)
__global__ void gemm3t(const u16* __restrict__ Ahi, const u16* __restrict__ Alo,
                       const u16* __restrict__ Bhi, const u16* __restrict__ Blo,
                       const float* __restrict__ bias,
                       float* __restrict__ Cf, u16* __restrict__ Chi, u16* __restrict__ Clo,
                       int N, int gn, int gmn,
                       long long sA, long long sB, long long sC)
{
    constexpr int REG  = 8192;                   // u16 per 256x32 region (16KB)
    constexpr int NRG  = DENSE ? 2 : 4;          // [Ahi][Alo][Bhi][Blo] | [A][B]
    constexpr int BUF  = NRG * REG;
    constexpr int O_AL = REG;                    // split only
    constexpr int O_BH = DENSE ? REG : 2 * REG;
    constexpr int O_BL = 3 * REG;                // split only
    __shared__ __align__(16) u16 lds[2 * BUF];

    const int tid  = threadIdx.x;
    const int lane = tid & 63;
    const int wv   = tid >> 6;
    const int wr   = wv >> 2, wc = wv & 3;       // 2M x 4N waves

    // XCD-contiguous block swizzle (nwg=256 -> 32 contiguous tiles/XCD)
    const int d   = blockIdx.x;
    const int cpx = gridDim.x >> 3;
    const int swz = (d & 7) * cpx + (d >> 3);
    const long long z = swz / gmn;
    const int r_  = swz % gmn;
    const int bm  = (r_ / gn) * 256;
    const int bn  = (r_ % gn) * 256;

    const char* pAh = (const char*)(Ahi + z * sA);
    const char* pAl = (const char*)(Alo + z * sA);
    const char* pBh = (const char*)(Bhi + z * sB);
    const char* pBl = (const char*)(Blo + z * sB);

    // ---- staging: region = 1024 x 16B chunks. chunk c: row=c>>2, phys
    // slot=c&3, src logical slot = (c&3)^(row&3). thread t stages chunks
    // {t, t+512} (rows r0, r0+128; same XOR). Row stride = 2048B everywhere.
    const int r0 = tid >> 2;                     // 0..127
    const int xc = (tid & 3) ^ (r0 & 3);
    const long long aof = (long long)(bm + r0) * 2048 + xc * 16;
    const long long bof = (long long)(bn + r0) * 2048 + xc * 16;
    const long long ao2 = aof + 128 * 2048;
    const long long bo2 = bof + 128 * 2048;
    const int d0 = tid * 8;                      // u16 dest offset (chunk t)
    const int d1 = d0 + 4096;                    // chunk t+512

    // ---- fragment ds_read offsets (u16 units within region), same swizzle
    int offA[8], offB[4];
#pragma unroll
    for (int i = 0; i < 8; ++i) {
        const int r = wr * 128 + i * 16 + (lane & 15);
        offA[i] = r * 32 + ((((lane >> 4) ^ r) & 3) << 3);
    }
#pragma unroll
    for (int j = 0; j < 4; ++j) {
        const int r = wc * 64 + j * 16 + (lane & 15);
        offB[j] = r * 32 + ((((lane >> 4) ^ r) & 3) << 3);
    }

    f32x4 acc[8][4];
#pragma unroll
    for (int i = 0; i < 8; ++i)
#pragma unroll
        for (int j = 0; j < 4; ++j)
            acc[i][j] = (f32x4){0.f, 0.f, 0.f, 0.f};

#define STG(NB, KB) do {                                                      \
        load_lds16((const u16*)(pAh + aof + (KB)), lds + (NB) + d0);          \
        load_lds16((const u16*)(pAh + ao2 + (KB)), lds + (NB) + d1);          \
        load_lds16((const u16*)(pBh + bof + (KB)), lds + (NB) + O_BH + d0);   \
        load_lds16((const u16*)(pBh + bo2 + (KB)), lds + (NB) + O_BH + d1);   \
        if constexpr (!DENSE) {                                               \
            load_lds16((const u16*)(pAl + aof + (KB)), lds + (NB) + O_AL + d0); \
            load_lds16((const u16*)(pAl + ao2 + (KB)), lds + (NB) + O_AL + d1); \
            load_lds16((const u16*)(pBl + bof + (KB)), lds + (NB) + O_BL + d0); \
            load_lds16((const u16*)(pBl + bo2 + (KB)), lds + (NB) + O_BL + d1); \
        }                                                                     \
    } while (0)

#define TERM(AF, BF) do {                                                     \
        __builtin_amdgcn_s_setprio(1);                                        \
        _Pragma("unroll")                                                     \
        for (int i = 0; i < 8; ++i)                                           \
            _Pragma("unroll")                                                 \
            for (int j = 0; j < 4; ++j)                                       \
                acc[i][j] = MFMA_B16(AF[i], BF[j], acc[i][j]);                \
        __builtin_amdgcn_s_setprio(0);                                        \
    } while (0)

    constexpr int NT = 32;                       // K=1024 / BK=32

    STG(0, 0);                                   // prologue: tile 0 -> buf 0

    for (int t = 0; t < NT; ++t) {
        const int cb = (t & 1) ? BUF : 0;
        const int nb = (t & 1) ? 0 : BUF;
        const long long kb = (long long)(t + 1) * 64;  // bytes

        VMW0();                  // tile t staged loads retired (per wave)
        SBAR();                  // cross-wave publish
        bf16x8 bh[4], bl[4], ah[8], al[8];
#pragma unroll
        for (int j = 0; j < 4; ++j) {
            bh[j] = *(const bf16x8*)(lds + cb + O_BH + offB[j]);
            if constexpr (!DENSE) bl[j] = *(const bf16x8*)(lds + cb + O_BL + offB[j]);
        }
#pragma unroll
        for (int i = 0; i < 8; ++i)
            ah[i] = *(const bf16x8*)(lds + cb + offA[i]);
        if (t + 1 < NT) STG(nb, kb);             // issue t+1 early (max slack)
        LGKM0(); SCHB();
        TERM(ah, bh);                            // T1: 32 MFMA
        if constexpr (!DENSE) {
#pragma unroll
            for (int i = 0; i < 8; ++i)
                al[i] = *(const bf16x8*)(lds + cb + O_AL + offA[i]);
            TERM(ah, bl);                        // T2 (al reads hide under T2)
            LGKM0(); SCHB();
            TERM(al, bh);                        // T3
        }
    }
#undef STG
#undef TERM

    // epilogue; C/D map: col = lane&15, row = (lane>>4)*4 + e  [m89/m91]
    const long long Cbase = z * sC;
#pragma unroll
    for (int i = 0; i < 8; ++i) {
        const int row0 = bm + wr * 128 + i * 16 + ((lane >> 4) << 2);
#pragma unroll
        for (int j = 0; j < 4; ++j) {
            const int col = bn + wc * 64 + j * 16 + (lane & 15);
#pragma unroll
            for (int e = 0; e < 4; ++e) {
                const float v = acc[i][j][e];
                const long long idx = Cbase + (long long)(row0 + e) * N + col;
                if constexpr (EPI == 0) {
                    Cf[idx] = v;
                } else if constexpr (EPI == 1) {
                    const float vb = v + bias[col];
                    const u16 h = f2bf(vb);
                    Chi[idx] = h;
                    Clo[idx] = f2bf(vb - bf2f(h));
                } else {
                    Cf[idx] = fmaxf(v, 0.f);
                }
            }
        }
    }
}

// fp32 -> bf16 hi/lo split, 4 elems/thread
__global__ void split_cvt(const float* __restrict__ in, u16* __restrict__ hi,
                          u16* __restrict__ lo, long long n4)
{
    const long long i = (long long)blockIdx.x * 256 + threadIdx.x;
    if (i >= n4) return;
    const float4 v = ((const float4*)in)[i];
    ushort4 h, l;
    h.x = f2bf(v.x); l.x = f2bf(v.x - bf2f(h.x));
    h.y = f2bf(v.y); l.y = f2bf(v.y - bf2f(h.y));
    h.z = f2bf(v.z); l.z = f2bf(v.z - bf2f(h.z));
    h.w = f2bf(v.w); l.w = f2bf(v.w - bf2f(h.w));
    ((ushort4*)hi)[i] = h;
    ((ushort4*)lo)[i] = l;
}

// fused q pre-pass: read q once per 32x32 tile -> write q_hi, q_lo (straight)
// and qT_hi (transposed). Saves one full 64MB read of q vs separate kernels.
__global__ void fuse_cvt_q(const float* __restrict__ q, u16* __restrict__ hi,
                           u16* __restrict__ lo, u16* __restrict__ thi)
{
    __shared__ float t[32][33];
    const long long z = blockIdx.z;
    const long long base = z * 1048576;
    const int r0 = blockIdx.y * 32, c0 = blockIdx.x * 32;
    for (int j = threadIdx.y; j < 32; j += 8) {
        const float v = q[base + (long long)(r0 + j) * 1024 + c0 + threadIdx.x];
        t[j][threadIdx.x] = v;
        const long long o = base + (long long)(r0 + j) * 1024 + c0 + threadIdx.x;
        const u16 h = f2bf(v);
        hi[o] = h;
        lo[o] = f2bf(v - bf2f(h));
    }
    __syncthreads();
    for (int j = threadIdx.y; j < 32; j += 8)
        thi[base + (long long)(c0 + j) * 1024 + r0 + threadIdx.x] = f2bf(t[threadIdx.x][j]);
}

// out[c][r] = in[r][c] with bf16 hi/lo conversion (W pre-pass)
__global__ void transpose_cvt_w(const float* __restrict__ in, u16* __restrict__ hi,
                                u16* __restrict__ lo)
{
    __shared__ float t[32][33];
    const int r0 = blockIdx.y * 32, c0 = blockIdx.x * 32;
    for (int j = threadIdx.y; j < 32; j += 8)
        t[j][threadIdx.x] = in[(long long)(r0 + j) * 1024 + c0 + threadIdx.x];
    __syncthreads();
    for (int j = threadIdx.y; j < 32; j += 8) {
        const float v = t[threadIdx.x][j];
        const long long o = (long long)(c0 + j) * 1024 + r0 + threadIdx.x;
        const u16 h = f2bf(v);
        hi[o] = h;
        lo[o] = f2bf(v - bf2f(h));
    }
}

// row softmax (fp32 in, bf16 out), one 256-thread block per 1024-elem row
__global__ void softmax_bf16(const float* __restrict__ S, u16* __restrict__ A)
{
    const long long row = blockIdx.x;
    const float* r = S + row * (long long)LQ_N;
    const int t = threadIdx.x;
    float4 v = ((const float4*)r)[t];

    float m = fmaxf(fmaxf(v.x, v.y), fmaxf(v.z, v.w));
#pragma unroll
    for (int off = 32; off > 0; off >>= 1)
        m = fmaxf(m, __shfl_xor(m, off));

    __shared__ float red[4];
    const int lane = t & 63, wid = t >> 6;
    if (lane == 0) red[wid] = m;
    __syncthreads();
    m = fmaxf(fmaxf(red[0], red[1]), fmaxf(red[2], red[3]));
    __syncthreads();

    v.x = __expf(v.x - m); v.y = __expf(v.y - m);
    v.z = __expf(v.z - m); v.w = __expf(v.w - m);
    float s = v.x + v.y + v.z + v.w;
#pragma unroll
    for (int off = 32; off > 0; off >>= 1)
        s += __shfl_xor(s, off);
    if (lane == 0) red[wid] = s;
    __syncthreads();
    s = red[0] + red[1] + red[2] + red[3];

    const float inv = 1.0f / s;
    ushort4 o;
    o.x = f2bf(v.x * inv); o.y = f2bf(v.y * inv);
    o.z = f2bf(v.z * inv); o.w = f2bf(v.w * inv);
    ((ushort4*)(A + row * (long long)LQ_N))[t] = o;
}

// ---------------------------------------------------------------------------
// Fallback fp32 path (round-1, verified; needs only 128 MB ws)
// ---------------------------------------------------------------------------
#define BM 128
#define BN 128
#define BK 8
#define TM 8
#define TN 8

template<bool TRANSB, bool BIAS, bool RELU>
__launch_bounds__(256)
__global__ void gemm_k(const float* __restrict__ A, const float* __restrict__ Bmat,
                       const float* __restrict__ bias, float* __restrict__ C,
                       int M, int N, int K,
                       long long sA, long long sB, long long sC)
{
    __shared__ float As[BK][BM];
    __shared__ float Bs[BK][BN];
    const int tid = threadIdx.x;
    const int tx = tid & 15;
    const int ty = tid >> 4;
    const int bn = blockIdx.x * BN;
    const int bm = blockIdx.y * BM;
    const long long z = blockIdx.z;
    A += z * sA; Bmat += z * sB; C += z * sC;
    float acc[TM][TN];
#pragma unroll
    for (int i = 0; i < TM; i++)
#pragma unroll
        for (int j = 0; j < TN; j++) acc[i][j] = 0.f;
    const int arow = tid >> 1;
    const int acol = (tid & 1) * 4;
    const int bk_n = tid >> 5;
    const int bn_n = (tid & 31) * 4;
    for (int k0 = 0; k0 < K; k0 += BK) {
        float4 a4 = *(const float4*)&A[(long long)(bm + arow) * K + k0 + acol];
        As[acol + 0][arow] = a4.x; As[acol + 1][arow] = a4.y;
        As[acol + 2][arow] = a4.z; As[acol + 3][arow] = a4.w;
        if (TRANSB) {
            float4 b4 = *(const float4*)&Bmat[(long long)(bn + arow) * K + k0 + acol];
            Bs[acol + 0][arow] = b4.x; Bs[acol + 1][arow] = b4.y;
            Bs[acol + 2][arow] = b4.z; Bs[acol + 3][arow] = b4.w;
        } else {
            float4 b4 = *(const float4*)&Bmat[(long long)(k0 + bk_n) * N + bn + bn_n];
            *(float4*)&Bs[bk_n][bn_n] = b4;
        }
        __syncthreads();
#pragma unroll
        for (int k = 0; k < BK; k++) {
            float a[TM], b[TN];
            *(float4*)&a[0] = *(const float4*)&As[k][ty * TM];
            *(float4*)&a[4] = *(const float4*)&As[k][ty * TM + 4];
            *(float4*)&b[0] = *(const float4*)&Bs[k][tx * TN];
            *(float4*)&b[4] = *(const float4*)&Bs[k][tx * TN + 4];
#pragma unroll
            for (int i = 0; i < TM; i++)
#pragma unroll
                for (int j = 0; j < TN; j++)
                    acc[i][j] = fmaf(a[i], b[j], acc[i][j]);
        }
        __syncthreads();
    }
#pragma unroll
    for (int i = 0; i < TM; i++) {
        const int row = bm + ty * TM + i;
#pragma unroll
        for (int j = 0; j < TN; j += 4) {
            const int col = bn + tx * TN + j;
            float4 v;
            v.x = acc[i][j + 0]; v.y = acc[i][j + 1];
            v.z = acc[i][j + 2]; v.w = acc[i][j + 3];
            if (BIAS) {
                v.x += bias[col + 0]; v.y += bias[col + 1];
                v.z += bias[col + 2]; v.w += bias[col + 3];
            }
            if (RELU) {
                v.x = fmaxf(v.x, 0.f); v.y = fmaxf(v.y, 0.f);
                v.z = fmaxf(v.z, 0.f); v.w = fmaxf(v.w, 0.f);
            }
            *(float4*)&C[(long long)row * N + col] = v;
        }
    }
}

__global__ void softmax_k(float* __restrict__ S)
{
    const long long row = blockIdx.x;
    float* r = S + row * (long long)LQ_N;
    const int t = threadIdx.x;
    float4 v = ((float4*)r)[t];
    float m = fmaxf(fmaxf(v.x, v.y), fmaxf(v.z, v.w));
#pragma unroll
    for (int off = 32; off > 0; off >>= 1)
        m = fmaxf(m, __shfl_xor(m, off));
    __shared__ float red[4];
    const int lane = t & 63, wid = t >> 6;
    if (lane == 0) red[wid] = m;
    __syncthreads();
    m = fmaxf(fmaxf(red[0], red[1]), fmaxf(red[2], red[3]));
    __syncthreads();
    v.x = __expf(v.x - m); v.y = __expf(v.y - m);
    v.z = __expf(v.z - m); v.w = __expf(v.w - m);
    float s = v.x + v.y + v.z + v.w;
#pragma unroll
    for (int off = 32; off > 0; off >>= 1)
        s += __shfl_xor(s, off);
    if (lane == 0) red[wid] = s;
    __syncthreads();
    s = red[0] + red[1] + red[2] + red[3];
    const float inv = 1.0f / s;
    v.x *= inv; v.y *= inv; v.z *= inv; v.w *= inv;
    ((float4*)r)[t] = v;
}

extern "C" void kernel_launch(void* const* d_in, const int* in_sizes, int n_in,
                              void* d_out, int out_size, void* d_ws, size_t ws_size,
                              hipStream_t stream)
{
    const float* p    = (const float*)d_in[0];
    const float* q    = (const float*)d_in[1];
    const float* W    = (const float*)d_in[2];
    const float* bias = (const float*)d_in[3];
    float* out = (float*)d_out;

    const size_t MB32 = 33554432ull;                 // 16M bf16
    const size_t NEED = 7 * MB32 + 2 * 2097152ull;   // 228 MB + 4 MB

    if (ws_size >= NEED) {
        char* w = (char*)d_ws;
        u16* p_hi    = (u16*)(w + 0 * MB32);
        u16* p_lo    = (u16*)(w + 1 * MB32);
        u16* q_hi    = (u16*)(w + 2 * MB32);
        u16* q_lo    = (u16*)(w + 3 * MB32);
        u16* keys_hi = (u16*)(w + 4 * MB32);
        u16* keys_lo = (u16*)(w + 5 * MB32);
        u16* qT_hi   = (u16*)(w + 6 * MB32);
        u16* Wt_hi   = (u16*)(w + 7 * MB32);
        u16* Wt_lo   = (u16*)(w + 7 * MB32 + 2097152);
        float* scores = (float*)(w + 2 * MB32);  // reuses q_hi/q_lo after GEMM1
        u16* attn     = (u16*)(w + 0 * MB32);    // reuses p_hi after GEMM2

        const long long n4 = (long long)B_N * LQ_N * H_N / 4;
        split_cvt<<<dim3((unsigned)(n4 / 256)), 256, 0, stream>>>(p, p_hi, p_lo, n4);
        fuse_cvt_q<<<dim3(32, 32, B_N), dim3(32, 8), 0, stream>>>(q, q_hi, q_lo, qT_hi);
        transpose_cvt_w<<<dim3(32, 32, 1), dim3(32, 8), 0, stream>>>(W, Wt_hi, Wt_lo);

        // keys = q @ W + b : split 3-term shared staging. M=16384, N=1024.
        gemm3t<false, 1><<<256, 512, 0, stream>>>(
            q_hi, q_lo, Wt_hi, Wt_lo, bias, nullptr, keys_hi, keys_lo,
            H_N, /*gn=*/4, /*gmn=*/256, 0, 0, 0);

        // scores[b] = p[b] @ keys[b]^T
        gemm3t<false, 0><<<256, 512, 0, stream>>>(
            p_hi, p_lo, keys_hi, keys_lo, nullptr, scores, nullptr, nullptr,
            LQ_N, /*gn=*/4, /*gmn=*/16,
            (long long)LP_N * H_N, (long long)LQ_N * H_N, (long long)LP_N * LQ_N);

        softmax_bf16<<<B_N * LP_N, 256, 0, stream>>>(scores, attn);

        // out[b] = relu(attn[b] @ q[b]) : dense bf16 (A=attn, B=qT).
        gemm3t<true, 2><<<256, 512, 0, stream>>>(
            attn, attn, qT_hi, qT_hi, nullptr, out, nullptr, nullptr,
            H_N, /*gn=*/4, /*gmn=*/16,
            (long long)LP_N * LQ_N, (long long)H_N * LQ_N, (long long)LP_N * H_N);
    } else {
        float* keys   = (float*)d_ws;
        float* scores = keys + (long long)B_N * LQ_N * H_N;

        gemm_k<false, true, false><<<dim3(H_N / BN, (B_N * LQ_N) / BM, 1), 256, 0, stream>>>(
            q, W, bias, keys, B_N * LQ_N, H_N, H_N, 0, 0, 0);
        gemm_k<true, false, false><<<dim3(LQ_N / BN, LP_N / BM, B_N), 256, 0, stream>>>(
            p, keys, nullptr, scores, LP_N, LQ_N, H_N,
            (long long)LP_N * H_N, (long long)LQ_N * H_N, (long long)LP_N * LQ_N);
        softmax_k<<<B_N * LP_N, 256, 0, stream>>>(scores);
        gemm_k<false, false, true><<<dim3(H_N / BN, LP_N / BM, B_N), 256, 0, stream>>>(
            scores, q, nullptr, out, LP_N, H_N, LQ_N,
            (long long)LP_N * LQ_N, (long long)LQ_N * H_N, (long long)LP_N * H_N);
    }
}

// Round 9
// 305.995 us; speedup vs baseline: 1.0347x; 1.0126x over previous
//
#include <hip/hip_runtime.h>
#include <hip/hip_bf16.h>

#define B_N 16
#define LP_N 1024
#define LQ_N 1024
#define H_N 1024

typedef unsigned short u16;
typedef __attribute__((ext_vector_type(8))) short bf16x8;
typedef __attribute__((ext_vector_type(4))) float f32x4;

__device__ __forceinline__ u16 f2bf(float x) {
    __hip_bfloat16 h = __float2bfloat16(x);
    return *(u16*)&h;
}
__device__ __forceinline__ float bf2f(u16 u) {
    __hip_bfloat16 h;
    *(u16*)&h = u;
    return __bfloat162float(h);
}

__device__ __forceinline__ void load_lds16(const u16* g, u16* l) {
    __builtin_amdgcn_global_load_lds(
        (const __attribute__((address_space(1))) void*)g,
        (__attribute__((address_space(3))) void*)l, 16, 0, 0);
}

#define MFMA_B16(a, b, c) __builtin_amdgcn_mfma_f32_16x16x32_bf16(a, b, c, 0, 0, 0)
#define VMW0()  asm volatile("s_waitcnt vmcnt(0)" ::: "memory")
#define LGKM0() asm volatile("s_waitcnt lgkmcnt(0)" ::: "memory")
#define SCHB()  __builtin_amdgcn_sched_barrier(0)
#define SBAR()  __builtin_amdgcn_s_barrier()

// ---------------------------------------------------------------------------
// 256x256 split-bf16 MFMA GEMM, NT form, SHARED-OPERAND staging (R8 struct).
// R9 FIX: swizzle restored to the R3-verified family. With 64B rows
// (4 x 16B slots), bank parity == ROW parity, so the XOR must be constant
// within a row PAIR and cycle across pairs:  s_phys = s_log ^ ((row>>1)&3).
// R8's (row&3) left even-row lanes 4-deep on one bank group (6.29M
// conflicts measured). (row>>1)&3 -> 2 lanes/bank-group max = free (m136).
// Applied on BOTH pre-swizzled global staging source and frag ds_read
// offsets (rule #21). Everything else identical to R8:
//   BK=32 tiles staging {Ahi, Alo, Bhi, Blo} each once (4x16KB, dbuf 128KB),
//   3 split terms per tile (T2 reuses ah regs), 96 MFMA vs 24 ds_read/wave,
//   one vmcnt(0)+s_barrier per tile, t+1 staged right after front reads.
// DENSE=true: 2 regions {A, B}, T1 only (GEMM3).
// EPI: 0 = fp32 store, 1 = +bias & split bf16 hi/lo store, 2 = relu fp32.
// ---------------------------------------------------------------------------
template<bool DENSE, int EPI>
__launch_bounds__(512, 2)
__global__ void gemm3t(const u16* __restrict__ Ahi, const u16* __restrict__ Alo,
                       const u16* __restrict__ Bhi, const u16* __restrict__ Blo,
                       const float* __restrict__ bias,
                       float* __restrict__ Cf, u16* __restrict__ Chi, u16* __restrict__ Clo,
                       int N, int gn, int gmn,
                       long long sA, long long sB, long long sC)
{
    constexpr int REG  = 8192;                   // u16 per 256x32 region (16KB)
    constexpr int NRG  = DENSE ? 2 : 4;          // [Ahi][Alo][Bhi][Blo] | [A][B]
    constexpr int BUF  = NRG * REG;
    constexpr int O_AL = REG;                    // split only
    constexpr int O_BH = DENSE ? REG : 2 * REG;
    constexpr int O_BL = 3 * REG;                // split only
    __shared__ __align__(16) u16 lds[2 * BUF];

    const int tid  = threadIdx.x;
    const int lane = tid & 63;
    const int wv   = tid >> 6;
    const int wr   = wv >> 2, wc = wv & 3;       // 2M x 4N waves

    // XCD-contiguous block swizzle (nwg=256 -> 32 contiguous tiles/XCD)
    const int d   = blockIdx.x;
    const int cpx = gridDim.x >> 3;
    const int swz = (d & 7) * cpx + (d >> 3);
    const long long z = swz / gmn;
    const int r_  = swz % gmn;
    const int bm  = (r_ / gn) * 256;
    const int bn  = (r_ % gn) * 256;

    const char* pAh = (const char*)(Ahi + z * sA);
    const char* pAl = (const char*)(Alo + z * sA);
    const char* pBh = (const char*)(Bhi + z * sB);
    const char* pBl = (const char*)(Blo + z * sB);

    // ---- staging: region = 1024 x 16B chunks. chunk c: row=c>>2, phys
    // slot=c&3, src logical slot = (c&3)^((row>>1)&3). thread t stages chunks
    // {t, t+512} (rows r0, r0+128; same XOR since (r0+128)>>1 ≡ r0>>1 mod 4... 
    // (r0+128)>>1 = r0>>1 + 64, 64&3=0 ✓). Row stride = 2048B everywhere.
    const int r0 = tid >> 2;                     // 0..127
    const int xc = (tid & 3) ^ ((r0 >> 1) & 3);
    const long long aof = (long long)(bm + r0) * 2048 + xc * 16;
    const long long bof = (long long)(bn + r0) * 2048 + xc * 16;
    const long long ao2 = aof + 128 * 2048;
    const long long bo2 = bof + 128 * 2048;
    const int d0 = tid * 8;                      // u16 dest offset (chunk t)
    const int d1 = d0 + 4096;                    // chunk t+512

    // ---- fragment ds_read offsets (u16 units within region), same swizzle
    int offA[8], offB[4];
#pragma unroll
    for (int i = 0; i < 8; ++i) {
        const int r = wr * 128 + i * 16 + (lane & 15);
        offA[i] = r * 32 + ((((lane >> 4) ^ (r >> 1)) & 3) << 3);
    }
#pragma unroll
    for (int j = 0; j < 4; ++j) {
        const int r = wc * 64 + j * 16 + (lane & 15);
        offB[j] = r * 32 + ((((lane >> 4) ^ (r >> 1)) & 3) << 3);
    }

    f32x4 acc[8][4];
#pragma unroll
    for (int i = 0; i < 8; ++i)
#pragma unroll
        for (int j = 0; j < 4; ++j)
            acc[i][j] = (f32x4){0.f, 0.f, 0.f, 0.f};

#define STG(NB, KB) do {                                                      \
        load_lds16((const u16*)(pAh + aof + (KB)), lds + (NB) + d0);          \
        load_lds16((const u16*)(pAh + ao2 + (KB)), lds + (NB) + d1);          \
        load_lds16((const u16*)(pBh + bof + (KB)), lds + (NB) + O_BH + d0);   \
        load_lds16((const u16*)(pBh + bo2 + (KB)), lds + (NB) + O_BH + d1);   \
        if constexpr (!DENSE) {                                               \
            load_lds16((const u16*)(pAl + aof + (KB)), lds + (NB) + O_AL + d0); \
            load_lds16((const u16*)(pAl + ao2 + (KB)), lds + (NB) + O_AL + d1); \
            load_lds16((const u16*)(pBl + bof + (KB)), lds + (NB) + O_BL + d0); \
            load_lds16((const u16*)(pBl + bo2 + (KB)), lds + (NB) + O_BL + d1); \
        }                                                                     \
    } while (0)

#define TERM(AF, BF) do {                                                     \
        __builtin_amdgcn_s_setprio(1);                                        \
        _Pragma("unroll")                                                     \
        for (int i = 0; i < 8; ++i)                                           \
            _Pragma("unroll")                                                 \
            for (int j = 0; j < 4; ++j)                                       \
                acc[i][j] = MFMA_B16(AF[i], BF[j], acc[i][j]);                \
        __builtin_amdgcn_s_setprio(0);                                        \
    } while (0)

    constexpr int NT = 32;                       // K=1024 / BK=32

    STG(0, 0);                                   // prologue: tile 0 -> buf 0

    for (int t = 0; t < NT; ++t) {
        const int cb = (t & 1) ? BUF : 0;
        const int nb = (t & 1) ? 0 : BUF;
        const long long kb = (long long)(t + 1) * 64;  // bytes

        VMW0();                  // tile t staged loads retired (per wave)
        SBAR();                  // cross-wave publish
        bf16x8 bh[4], bl[4], ah[8], al[8];
#pragma unroll
        for (int j = 0; j < 4; ++j) {
            bh[j] = *(const bf16x8*)(lds + cb + O_BH + offB[j]);
            if constexpr (!DENSE) bl[j] = *(const bf16x8*)(lds + cb + O_BL + offB[j]);
        }
#pragma unroll
        for (int i = 0; i < 8; ++i)
            ah[i] = *(const bf16x8*)(lds + cb + offA[i]);
        if (t + 1 < NT) STG(nb, kb);             // issue t+1 early (max slack)
        LGKM0(); SCHB();
        TERM(ah, bh);                            // T1: 32 MFMA
        if constexpr (!DENSE) {
#pragma unroll
            for (int i = 0; i < 8; ++i)
                al[i] = *(const bf16x8*)(lds + cb + O_AL + offA[i]);
            TERM(ah, bl);                        // T2 (al reads hide under T2)
            LGKM0(); SCHB();
            TERM(al, bh);                        // T3
        }
    }
#undef STG
#undef TERM

    // epilogue; C/D map: col = lane&15, row = (lane>>4)*4 + e  [m89/m91]
    const long long Cbase = z * sC;
#pragma unroll
    for (int i = 0; i < 8; ++i) {
        const int row0 = bm + wr * 128 + i * 16 + ((lane >> 4) << 2);
#pragma unroll
        for (int j = 0; j < 4; ++j) {
            const int col = bn + wc * 64 + j * 16 + (lane & 15);
#pragma unroll
            for (int e = 0; e < 4; ++e) {
                const float v = acc[i][j][e];
                const long long idx = Cbase + (long long)(row0 + e) * N + col;
                if constexpr (EPI == 0) {
                    Cf[idx] = v;
                } else if constexpr (EPI == 1) {
                    const float vb = v + bias[col];
                    const u16 h = f2bf(vb);
                    Chi[idx] = h;
                    Clo[idx] = f2bf(vb - bf2f(h));
                } else {
                    Cf[idx] = fmaxf(v, 0.f);
                }
            }
        }
    }
}

// fp32 -> bf16 hi/lo split, 4 elems/thread
__global__ void split_cvt(const float* __restrict__ in, u16* __restrict__ hi,
                          u16* __restrict__ lo, long long n4)
{
    const long long i = (long long)blockIdx.x * 256 + threadIdx.x;
    if (i >= n4) return;
    const float4 v = ((const float4*)in)[i];
    ushort4 h, l;
    h.x = f2bf(v.x); l.x = f2bf(v.x - bf2f(h.x));
    h.y = f2bf(v.y); l.y = f2bf(v.y - bf2f(h.y));
    h.z = f2bf(v.z); l.z = f2bf(v.z - bf2f(h.z));
    h.w = f2bf(v.w); l.w = f2bf(v.w - bf2f(h.w));
    ((ushort4*)hi)[i] = h;
    ((ushort4*)lo)[i] = l;
}

// fused q pre-pass: read q once per 32x32 tile -> write q_hi, q_lo (straight)
// and qT_hi (transposed). Saves one full 64MB read of q vs separate kernels.
__global__ void fuse_cvt_q(const float* __restrict__ q, u16* __restrict__ hi,
                           u16* __restrict__ lo, u16* __restrict__ thi)
{
    __shared__ float t[32][33];
    const long long z = blockIdx.z;
    const long long base = z * 1048576;
    const int r0 = blockIdx.y * 32, c0 = blockIdx.x * 32;
    for (int j = threadIdx.y; j < 32; j += 8) {
        const float v = q[base + (long long)(r0 + j) * 1024 + c0 + threadIdx.x];
        t[j][threadIdx.x] = v;
        const long long o = base + (long long)(r0 + j) * 1024 + c0 + threadIdx.x;
        const u16 h = f2bf(v);
        hi[o] = h;
        lo[o] = f2bf(v - bf2f(h));
    }
    __syncthreads();
    for (int j = threadIdx.y; j < 32; j += 8)
        thi[base + (long long)(c0 + j) * 1024 + r0 + threadIdx.x] = f2bf(t[threadIdx.x][j]);
}

// out[c][r] = in[r][c] with bf16 hi/lo conversion (W pre-pass)
__global__ void transpose_cvt_w(const float* __restrict__ in, u16* __restrict__ hi,
                                u16* __restrict__ lo)
{
    __shared__ float t[32][33];
    const int r0 = blockIdx.y * 32, c0 = blockIdx.x * 32;
    for (int j = threadIdx.y; j < 32; j += 8)
        t[j][threadIdx.x] = in[(long long)(r0 + j) * 1024 + c0 + threadIdx.x];
    __syncthreads();
    for (int j = threadIdx.y; j < 32; j += 8) {
        const float v = t[threadIdx.x][j];
        const long long o = (long long)(c0 + j) * 1024 + r0 + threadIdx.x;
        const u16 h = f2bf(v);
        hi[o] = h;
        lo[o] = f2bf(v - bf2f(h));
    }
}

// row softmax (fp32 in, bf16 out), one 256-thread block per 1024-elem row
__global__ void softmax_bf16(const float* __restrict__ S, u16* __restrict__ A)
{
    const long long row = blockIdx.x;
    const float* r = S + row * (long long)LQ_N;
    const int t = threadIdx.x;
    float4 v = ((const float4*)r)[t];

    float m = fmaxf(fmaxf(v.x, v.y), fmaxf(v.z, v.w));
#pragma unroll
    for (int off = 32; off > 0; off >>= 1)
        m = fmaxf(m, __shfl_xor(m, off));

    __shared__ float red[4];
    const int lane = t & 63, wid = t >> 6;
    if (lane == 0) red[wid] = m;
    __syncthreads();
    m = fmaxf(fmaxf(red[0], red[1]), fmaxf(red[2], red[3]));
    __syncthreads();

    v.x = __expf(v.x - m); v.y = __expf(v.y - m);
    v.z = __expf(v.z - m); v.w = __expf(v.w - m);
    float s = v.x + v.y + v.z + v.w;
#pragma unroll
    for (int off = 32; off > 0; off >>= 1)
        s += __shfl_xor(s, off);
    if (lane == 0) red[wid] = s;
    __syncthreads();
    s = red[0] + red[1] + red[2] + red[3];

    const float inv = 1.0f / s;
    ushort4 o;
    o.x = f2bf(v.x * inv); o.y = f2bf(v.y * inv);
    o.z = f2bf(v.z * inv); o.w = f2bf(v.w * inv);
    ((ushort4*)(A + row * (long long)LQ_N))[t] = o;
}

// ---------------------------------------------------------------------------
// Fallback fp32 path (round-1, verified; needs only 128 MB ws)
// ---------------------------------------------------------------------------
#define BM 128
#define BN 128
#define BK 8
#define TM 8
#define TN 8

template<bool TRANSB, bool BIAS, bool RELU>
__launch_bounds__(256)
__global__ void gemm_k(const float* __restrict__ A, const float* __restrict__ Bmat,
                       const float* __restrict__ bias, float* __restrict__ C,
                       int M, int N, int K,
                       long long sA, long long sB, long long sC)
{
    __shared__ float As[BK][BM];
    __shared__ float Bs[BK][BN];
    const int tid = threadIdx.x;
    const int tx = tid & 15;
    const int ty = tid >> 4;
    const int bn = blockIdx.x * BN;
    const int bm = blockIdx.y * BM;
    const long long z = blockIdx.z;
    A += z * sA; Bmat += z * sB; C += z * sC;
    float acc[TM][TN];
#pragma unroll
    for (int i = 0; i < TM; i++)
#pragma unroll
        for (int j = 0; j < TN; j++) acc[i][j] = 0.f;
    const int arow = tid >> 1;
    const int acol = (tid & 1) * 4;
    const int bk_n = tid >> 5;
    const int bn_n = (tid & 31) * 4;
    for (int k0 = 0; k0 < K; k0 += BK) {
        float4 a4 = *(const float4*)&A[(long long)(bm + arow) * K + k0 + acol];
        As[acol + 0][arow] = a4.x; As[acol + 1][arow] = a4.y;
        As[acol + 2][arow] = a4.z; As[acol + 3][arow] = a4.w;
        if (TRANSB) {
            float4 b4 = *(const float4*)&Bmat[(long long)(bn + arow) * K + k0 + acol];
            Bs[acol + 0][arow] = b4.x; Bs[acol + 1][arow] = b4.y;
            Bs[acol + 2][arow] = b4.z; Bs[acol + 3][arow] = b4.w;
        } else {
            float4 b4 = *(const float4*)&Bmat[(long long)(k0 + bk_n) * N + bn + bn_n];
            *(float4*)&Bs[bk_n][bn_n] = b4;
        }
        __syncthreads();
#pragma unroll
        for (int k = 0; k < BK; k++) {
            float a[TM], b[TN];
            *(float4*)&a[0] = *(const float4*)&As[k][ty * TM];
            *(float4*)&a[4] = *(const float4*)&As[k][ty * TM + 4];
            *(float4*)&b[0] = *(const float4*)&Bs[k][tx * TN];
            *(float4*)&b[4] = *(const float4*)&Bs[k][tx * TN + 4];
#pragma unroll
            for (int i = 0; i < TM; i++)
#pragma unroll
                for (int j = 0; j < TN; j++)
                    acc[i][j] = fmaf(a[i], b[j], acc[i][j]);
        }
        __syncthreads();
    }
#pragma unroll
    for (int i = 0; i < TM; i++) {
        const int row = bm + ty * TM + i;
#pragma unroll
        for (int j = 0; j < TN; j += 4) {
            const int col = bn + tx * TN + j;
            float4 v;
            v.x = acc[i][j + 0]; v.y = acc[i][j + 1];
            v.z = acc[i][j + 2]; v.w = acc[i][j + 3];
            if (BIAS) {
                v.x += bias[col + 0]; v.y += bias[col + 1];
                v.z += bias[col + 2]; v.w += bias[col + 3];
            }
            if (RELU) {
                v.x = fmaxf(v.x, 0.f); v.y = fmaxf(v.y, 0.f);
                v.z = fmaxf(v.z, 0.f); v.w = fmaxf(v.w, 0.f);
            }
            *(float4*)&C[(long long)row * N + col] = v;
        }
    }
}

__global__ void softmax_k(float* __restrict__ S)
{
    const long long row = blockIdx.x;
    float* r = S + row * (long long)LQ_N;
    const int t = threadIdx.x;
    float4 v = ((float4*)r)[t];
    float m = fmaxf(fmaxf(v.x, v.y), fmaxf(v.z, v.w));
#pragma unroll
    for (int off = 32; off > 0; off >>= 1)
        m = fmaxf(m, __shfl_xor(m, off));
    __shared__ float red[4];
    const int lane = t & 63, wid = t >> 6;
    if (lane == 0) red[wid] = m;
    __syncthreads();
    m = fmaxf(fmaxf(red[0], red[1]), fmaxf(red[2], red[3]));
    __syncthreads();
    v.x = __expf(v.x - m); v.y = __expf(v.y - m);
    v.z = __expf(v.z - m); v.w = __expf(v.w - m);
    float s = v.x + v.y + v.z + v.w;
#pragma unroll
    for (int off = 32; off > 0; off >>= 1)
        s += __shfl_xor(s, off);
    if (lane == 0) red[wid] = s;
    __syncthreads();
    s = red[0] + red[1] + red[2] + red[3];
    const float inv = 1.0f / s;
    v.x *= inv; v.y *= inv; v.z *= inv; v.w *= inv;
    ((float4*)r)[t] = v;
}

extern "C" void kernel_launch(void* const* d_in, const int* in_sizes, int n_in,
                              void* d_out, int out_size, void* d_ws, size_t ws_size,
                              hipStream_t stream)
{
    const float* p    = (const float*)d_in[0];
    const float* q    = (const float*)d_in[1];
    const float* W    = (const float*)d_in[2];
    const float* bias = (const float*)d_in[3];
    float* out = (float*)d_out;

    const size_t MB32 = 33554432ull;                 // 16M bf16
    const size_t NEED = 7 * MB32 + 2 * 2097152ull;   // 228 MB + 4 MB

    if (ws_size >= NEED) {
        char* w = (char*)d_ws;
        u16* p_hi    = (u16*)(w + 0 * MB32);
        u16* p_lo    = (u16*)(w + 1 * MB32);
        u16* q_hi    = (u16*)(w + 2 * MB32);
        u16* q_lo    = (u16*)(w + 3 * MB32);
        u16* keys_hi = (u16*)(w + 4 * MB32);
        u16* keys_lo = (u16*)(w + 5 * MB32);
        u16* qT_hi   = (u16*)(w + 6 * MB32);
        u16* Wt_hi   = (u16*)(w + 7 * MB32);
        u16* Wt_lo   = (u16*)(w + 7 * MB32 + 2097152);
        float* scores = (float*)(w + 2 * MB32);  // reuses q_hi/q_lo after GEMM1
        u16* attn     = (u16*)(w + 0 * MB32);    // reuses p_hi after GEMM2

        const long long n4 = (long long)B_N * LQ_N * H_N / 4;
        split_cvt<<<dim3((unsigned)(n4 / 256)), 256, 0, stream>>>(p, p_hi, p_lo, n4);
        fuse_cvt_q<<<dim3(32, 32, B_N), dim3(32, 8), 0, stream>>>(q, q_hi, q_lo, qT_hi);
        transpose_cvt_w<<<dim3(32, 32, 1), dim3(32, 8), 0, stream>>>(W, Wt_hi, Wt_lo);

        // keys = q @ W + b : split 3-term shared staging. M=16384, N=1024.
        gemm3t<false, 1><<<256, 512, 0, stream>>>(
            q_hi, q_lo, Wt_hi, Wt_lo, bias, nullptr, keys_hi, keys_lo,
            H_N, /*gn=*/4, /*gmn=*/256, 0, 0, 0);

        // scores[b] = p[b] @ keys[b]^T
        gemm3t<false, 0><<<256, 512, 0, stream>>>(
            p_hi, p_lo, keys_hi, keys_lo, nullptr, scores, nullptr, nullptr,
            LQ_N, /*gn=*/4, /*gmn=*/16,
            (long long)LP_N * H_N, (long long)LQ_N * H_N, (long long)LP_N * LQ_N);

        softmax_bf16<<<B_N * LP_N, 256, 0, stream>>>(scores, attn);

        // out[b] = relu(attn[b] @ q[b]) : dense bf16 (A=attn, B=qT).
        gemm3t<true, 2><<<256, 512, 0, stream>>>(
            attn, attn, qT_hi, qT_hi, nullptr, out, nullptr, nullptr,
            H_N, /*gn=*/4, /*gmn=*/16,
            (long long)LP_N * LQ_N, (long long)H_N * LQ_N, (long long)LP_N * H_N);
    } else {
        float* keys   = (float*)d_ws;
        float* scores = keys + (long long)B_N * LQ_N * H_N;

        gemm_k<false, true, false><<<dim3(H_N / BN, (B_N * LQ_N) / BM, 1), 256, 0, stream>>>(
            q, W, bias, keys, B_N * LQ_N, H_N, H_N, 0, 0, 0);
        gemm_k<true, false, false><<<dim3(LQ_N / BN, LP_N / BM, B_N), 256, 0, stream>>>(
            p, keys, nullptr, scores, LP_N, LQ_N, H_N,
            (long long)LP_N * H_N, (long long)LQ_N * H_N, (long long)LP_N * LQ_N);
        softmax_k<<<B_N * LP_N, 256, 0, stream>>>(scores);
        gemm_k<false, false, true><<<dim3(H_N / BN, LP_N / BM, B_N), 256, 0, stream>>>(
            scores, q, nullptr, out, LP_N, H_N, LQ_N,
            (long long)LP_N * LQ_N, (long long)LQ_N * H_N, (long long)LP_N * H_N);
    }
}